// Round 3
// baseline (312.611 us; speedup 1.0000x reference)
//
#include <hip/hip_runtime.h>
#include <stdint.h>

#define NG 4
#define NK 160
#define GD 128
#define ED 512
#define BB 16
#define TT 4096
#define NTOK (BB * TT)
static constexpr size_t ZSZ = (size_t)BB * ED * TT;           // 33554432
static constexpr size_t OSZ = ZSZ + 1 + (size_t)BB * NG * TT; // 33816577

// d_out is FLOAT32 (reference outputs are f32; harness reads np.float32).
// Layout: [0,ZSZ) z_q | [ZSZ] loss | [ZSZ+1, OSZ) codes (as float).
// ws: [0,4096) bsum f32 | [4096,4736) sc f32.

// ---------------- pass 1: codeword squared norms ----------------
__global__ void sc_kernel(const float* __restrict__ cb, float* __restrict__ sc) {
  int i = blockIdx.x * blockDim.x + threadIdx.x;
  if (i >= NG * NK) return;
  const float* c = cb + (size_t)i * GD;
  float s = 0.f;
  for (int d = 0; d < GD; ++d) s = fmaf(c[d], c[d], s);
  sc[i] = s;
}

// ---------------- pass 2: fused argmin + z_q scatter + codes + loss partials
// One thread = one (token, group); lane == t so all global accesses at a
// fixed channel are coalesced across the wave.
__global__ __launch_bounds__(64) void vq_kernel(const float* __restrict__ xin,
                                                const float* __restrict__ cb,
                                                const float* __restrict__ sc,
                                                float* __restrict__ out,
                                                float* __restrict__ bsum) {
  const int g = (int)(blockIdx.x >> 10);                  // 1024 blocks per group
  const int n = (int)((blockIdx.x & 1023) * 64 + threadIdx.x);
  const int b = n >> 12;
  const int t = n & 4095;

  const float* xp = xin + ((size_t)b * ED + (size_t)g * GD) * TT + t;
  float x[GD];
#pragma unroll
  for (int d = 0; d < GD; ++d) x[d] = xp[(size_t)d * TT];

  float sx = 0.f;
#pragma unroll
  for (int d = 0; d < GD; ++d) sx = fmaf(x[d], x[d], sx);

  const float* cbg = cb + (size_t)g * NK * GD;
  const float* scg = sc + g * NK;

  float best = 3.4e38f;
  int bik = 0;
  for (int k0 = 0; k0 < NK; k0 += 8) {                    // 20 iterations
    const float* cbk = cbg + (size_t)k0 * GD;
    float acc[8] = {0.f, 0.f, 0.f, 0.f, 0.f, 0.f, 0.f, 0.f};
#pragma unroll
    for (int d = 0; d < GD; ++d) {
#pragma unroll
      for (int kk = 0; kk < 8; ++kk)
        acc[kk] = fmaf(x[d], cbk[(size_t)kk * GD + d], acc[kk]);
    }
#pragma unroll
    for (int kk = 0; kk < 8; ++kk) {
      float dk = (sx + scg[k0 + kk]) - 2.0f * acc[kk];    // ref formula order
      if (dk < best) { best = dk; bik = k0 + kk; }        // first-min tie-break
    }
  }

  // codes_out[b, g, t] (float-encoded int)
  out[ZSZ + 1 + ((size_t)b * NG + g) * TT + t] = (float)bik;

  // z_q_out[b, g*128+d, t] = codebook[g, bik, d]
  const float4* cw = (const float4*)(cbg + (size_t)bik * GD);
  float* zp = out + ((size_t)b * ED + (size_t)g * GD) * TT + t;
#pragma unroll
  for (int d4 = 0; d4 < GD / 4; ++d4) {
    float4 v = cw[d4];
    zp[(size_t)(4 * d4 + 0) * TT] = v.x;
    zp[(size_t)(4 * d4 + 1) * TT] = v.y;
    zp[(size_t)(4 * d4 + 2) * TT] = v.z;
    zp[(size_t)(4 * d4 + 3) * TT] = v.w;
  }

  // loss partial: best == ||x - c_best||^2; deterministic wave reduce.
  float s = best;
#pragma unroll
  for (int off = 32; off > 0; off >>= 1) s += __shfl_down(s, off, 64);
  if (threadIdx.x == 0) bsum[blockIdx.x] = s;
}

// ---------------- pass 3: loss ----------------
__global__ __launch_bounds__(64) void loss_kernel(const float* __restrict__ bsum,
                                                  float* __restrict__ out) {
  float s = 0.f;
  for (int j = 0; j < 64; ++j) s += bsum[threadIdx.x + 64 * j];
#pragma unroll
  for (int off = 32; off > 0; off >>= 1) s += __shfl_down(s, off, 64);
  if (threadIdx.x == 0)
    out[ZSZ] = 1.25f * s / (float)ZSZ;
}

extern "C" void kernel_launch(void* const* d_in, const int* in_sizes, int n_in,
                              void* d_out, int out_size, void* d_ws, size_t ws_size,
                              hipStream_t stream) {
  const float* xin = (const float*)d_in[0];
  const float* cb  = (const float*)d_in[1];
  float* out  = (float*)d_out;
  float* bsum = (float*)d_ws;        // 4096 block partial sums
  float* sc   = bsum + 4096;         // 640 codeword norms

  sc_kernel<<<10, 64, 0, stream>>>(cb, sc);
  vq_kernel<<<4096, 64, 0, stream>>>(xin, cb, sc, out, bsum);
  loss_kernel<<<1, 64, 0, stream>>>(bsum, out);
}